// Round 3
// baseline (19426.205 us; speedup 1.0000x reference)
//
#include <hip/hip_runtime.h>
#include <cstdint>
#include <cstddef>

// ---------------------------------------------------------------------------
// PeriodicalPatchMixer — fp32, workspace-lean version (~157 MB, adapts down)
// B=64, FN=512, L=768, TOP_K=3, TPL=16
// ---------------------------------------------------------------------------

constexpr int B_   = 64;
constexpr int FN_  = 512;
constexpr int L_   = 768;
constexpr int C_   = FN_ * L_;       // 393216
constexpr int NSIG = B_ * FN_;       // 32768 signals for DFT
constexpr int NFRQ = 385;            // L/2 + 1
constexpr int NCOL = 770;            // interleaved cos/sin columns
constexpr int NPAD = 896;            // 7 * 128 padded N for DFT GEMM
constexpr int NMAX = 192;            // worst-case n (p = 4)
constexpr int FCAP = NMAX * 16;      // 3072 flat rows capacity per batch
constexpr float EPS_ = 1e-5f;

#define DEV_INLINE __device__ __forceinline__

DEV_INLINE float gelu_f(float v) {
    return 0.5f * v * (1.0f + erff(v * 0.70710678118654752440f));
}

// ---------------------------------------------------------------------------
// BN statistics over batch dim: scale[c] = rsqrt(var+eps)*g, shift[c] = b - m*scale
// ---------------------------------------------------------------------------
__global__ void bn_stats_kernel(const float* __restrict__ xin,
                                const float* __restrict__ gamma,
                                const float* __restrict__ beta,
                                float* __restrict__ scale,
                                float* __restrict__ shift)
{
    int c4 = blockIdx.x * 256 + threadIdx.x;
    if (c4 >= C_ / 4) return;
    float s0 = 0, s1 = 0, s2 = 0, s3 = 0;
    float q0 = 0, q1 = 0, q2 = 0, q3 = 0;
    const float* px = xin + (size_t)c4 * 4;
#pragma unroll 4
    for (int b = 0; b < B_; ++b) {
        float4 v = *(const float4*)(px + (size_t)b * C_);
        s0 += v.x; s1 += v.y; s2 += v.z; s3 += v.w;
        q0 += v.x * v.x; q1 += v.y * v.y; q2 += v.z * v.z; q3 += v.w * v.w;
    }
    const float inv = 1.0f / (float)B_;
    float4 g  = ((const float4*)gamma)[c4];
    float4 bt = ((const float4*)beta)[c4];
    float m0 = s0 * inv, m1 = s1 * inv, m2 = s2 * inv, m3 = s3 * inv;
    float4 sc, sh;
    sc.x = rsqrtf(fmaxf(q0 * inv - m0 * m0, 0.0f) + EPS_) * g.x; sh.x = bt.x - m0 * sc.x;
    sc.y = rsqrtf(fmaxf(q1 * inv - m1 * m1, 0.0f) + EPS_) * g.y; sh.y = bt.y - m1 * sc.y;
    sc.z = rsqrtf(fmaxf(q2 * inv - m2 * m2, 0.0f) + EPS_) * g.z; sh.z = bt.z - m2 * sc.z;
    sc.w = rsqrtf(fmaxf(q3 * inv - m3 * m3, 0.0f) + EPS_) * g.w; sh.w = bt.w - m3 * sc.w;
    ((float4*)scale)[c4] = sc;
    ((float4*)shift)[c4] = sh;
}

// ---------------------------------------------------------------------------
// Apply input BN, write xs (B, L, FN) via LDS transpose.
// grid (L/32, FN/32, B), block (32, 8).
// ---------------------------------------------------------------------------
__global__ void bn_apply_xs_kernel(const float* __restrict__ x,
                                   const float* __restrict__ scale,
                                   const float* __restrict__ shift,
                                   float* __restrict__ xs)
{
    __shared__ float tile[32][33];
    const int b  = blockIdx.z;
    const int l0 = blockIdx.x * 32;
    const int f0 = blockIdx.y * 32;
    const int tx = threadIdx.x, ty = threadIdx.y;
#pragma unroll
    for (int j = 0; j < 4; ++j) {
        int f = f0 + ty + j * 8;
        int c = f * L_ + l0 + tx;
        tile[ty + j * 8][tx] = x[(size_t)b * C_ + c] * scale[c] + shift[c];
    }
    __syncthreads();
#pragma unroll
    for (int j = 0; j < 4; ++j) {
        int l = l0 + ty + j * 8;
        xs[((size_t)b * L_ + l) * FN_ + f0 + tx] = tile[tx][ty + j * 8];
    }
}

// ---------------------------------------------------------------------------
// DFT basis, cos/sin interleaved: tab2[l][2*fr] = cos(2*pi*l*fr/768),
// tab2[l][2*fr+1] = sin(...), cols >= 770 zero-padded.  Also zeroes freq.
// ---------------------------------------------------------------------------
__global__ void fill_tab2_kernel(float* __restrict__ tab2, float* __restrict__ freq)
{
    int i = blockIdx.x * 256 + threadIdx.x;
    if (blockIdx.x == 0 && threadIdx.x < 512) freq[threadIdx.x] = 0.0f;
    if (i >= 768 * NPAD) return;
    int l = i / NPAD, col = i - l * NPAD;
    float v = 0.0f;
    if (col < NCOL) {
        int fr = col >> 1;
        int m = (l * fr) % 768;
        float sn, cs;
        sincospif((float)m * (1.0f / 384.0f), &sn, &cs);
        v = (col & 1) ? sn : cs;
    }
    tab2[i] = v;
}

// ---------------------------------------------------------------------------
// DFT GEMM reading xs directly.  Signal m = b*FN + f; A[m][k] = xs[b][k][f]
// (contiguous in f for fixed k -> coalesced k-major tile loads, no transpose).
// Epilogue: |X| from adjacent (cos,sin) cols, shfl-reduce over the 8x16 m-rows
// of the thread group, atomicAdd into freq[fr].  Scale omitted (rank-invariant).
// grid (NPAD/128, NSIG/128), block 256.
// ---------------------------------------------------------------------------
__global__ __launch_bounds__(256, 2)
void dft_gemm_kernel(const float* __restrict__ xs, const float* __restrict__ tab2,
                     float* __restrict__ freq)
{
    __shared__ float As[16][132];
    __shared__ float Bs[16][132];
    float acc[8][8];
#pragma unroll
    for (int i = 0; i < 8; ++i)
#pragma unroll
        for (int j = 0; j < 8; ++j) acc[i][j] = 0.0f;

    const int m0 = blockIdx.y * 128;
    const int n0 = blockIdx.x * 128;
    const int b  = m0 >> 9;           // m0 / FN_
    const int f0 = m0 & 511;          // m0 % FN_
    const size_t xbase = (size_t)b * C_ + f0;
    const int lkk = (int)(threadIdx.x >> 5);       // 0..7
    const int lmm = (int)(threadIdx.x & 31) * 4;   // 0..124
    const int TM = (int)(threadIdx.x & 15);
    const int TN = (int)(threadIdx.x >> 4);

    for (int k0 = 0; k0 < 768; k0 += 16) {
        float4 va0 = *(const float4*)&xs[xbase + (size_t)(k0 + lkk) * FN_ + lmm];
        float4 va1 = *(const float4*)&xs[xbase + (size_t)(k0 + lkk + 8) * FN_ + lmm];
        float4 vb0 = *(const float4*)&tab2[(size_t)(k0 + lkk) * NPAD + n0 + lmm];
        float4 vb1 = *(const float4*)&tab2[(size_t)(k0 + lkk + 8) * NPAD + n0 + lmm];
        *(float4*)&As[lkk][lmm]     = va0;
        *(float4*)&As[lkk + 8][lmm] = va1;
        *(float4*)&Bs[lkk][lmm]     = vb0;
        *(float4*)&Bs[lkk + 8][lmm] = vb1;
        __syncthreads();
#pragma unroll
        for (int kk = 0; kk < 16; ++kk) {
            float4 a0 = *(const float4*)&As[kk][TM * 8];
            float4 a1 = *(const float4*)&As[kk][TM * 8 + 4];
            float4 b0 = *(const float4*)&Bs[kk][TN * 8];
            float4 b1 = *(const float4*)&Bs[kk][TN * 8 + 4];
            float am[8] = {a0.x, a0.y, a0.z, a0.w, a1.x, a1.y, a1.z, a1.w};
            float bb[8] = {b0.x, b0.y, b0.z, b0.w, b1.x, b1.y, b1.z, b1.w};
#pragma unroll
            for (int mi = 0; mi < 8; ++mi)
#pragma unroll
                for (int ni = 0; ni < 8; ++ni)
                    acc[mi][ni] = fmaf(am[mi], bb[ni], acc[mi][ni]);
        }
        __syncthreads();
    }

    // magnitude + partial reduction
    float part[4];
#pragma unroll
    for (int pr = 0; pr < 4; ++pr) {
        int col = n0 + TN * 8 + pr * 2;
        float s = 0.0f;
        if (col < NCOL) {
#pragma unroll
            for (int mi = 0; mi < 8; ++mi) {
                float re = acc[mi][pr * 2], im = acc[mi][pr * 2 + 1];
                s += sqrtf(re * re + im * im);
            }
        }
        part[pr] = s;
    }
#pragma unroll
    for (int off = 8; off > 0; off >>= 1) {
#pragma unroll
        for (int pr = 0; pr < 4; ++pr)
            part[pr] += __shfl_down(part[pr], off, 16);
    }
    if ((threadIdx.x & 15) == 0) {
#pragma unroll
        for (int pr = 0; pr < 4; ++pr) {
            int col = n0 + TN * 8 + pr * 2;
            if (col < NCOL) atomicAdd(&freq[col >> 1], part[pr]);
        }
    }
}

// ---------------------------------------------------------------------------
// Top-3 (excluding fr=0) -> {p, n, tgt} + softmax fusion weights.
// Matches jax.lax.top_k tie-break (lower index wins).
// ---------------------------------------------------------------------------
__global__ void topk_kernel(const float* __restrict__ freq,
                            const float* __restrict__ fusion_w,
                            int* __restrict__ metaI, float* __restrict__ metaF)
{
    const int lane = threadIdx.x;  // 64
    int ex0 = -1, ex1 = -1;
    int tops[3];
    for (int r = 0; r < 3; ++r) {
        float best = -1.0f; int bidx = 0x7fffffff;
        for (int f = 1 + lane; f < NFRQ; f += 64) {
            if (f == ex0 || f == ex1) continue;
            float v = freq[f];
            if (v > best) { best = v; bidx = f; }
        }
        for (int off = 32; off > 0; off >>= 1) {
            float ov = __shfl_down(best, off);
            int   oi = __shfl_down(bidx, off);
            if (ov > best || (ov == best && oi < bidx)) { best = ov; bidx = oi; }
        }
        bidx = __shfl(bidx, 0);
        tops[r] = bidx;
        if (r == 0) ex0 = bidx; else ex1 = bidx;
    }
    if (lane == 0) {
        float w0 = fusion_w[0], w1 = fusion_w[1], w2 = fusion_w[2];
        float mx = fmaxf(w0, fmaxf(w1, w2));
        float e0 = expf(w0 - mx), e1 = expf(w1 - mx), e2 = expf(w2 - mx);
        float inv = 1.0f / (e0 + e1 + e2);
        metaF[0] = e0 * inv; metaF[1] = e1 * inv; metaF[2] = e2 * inv;
        for (int r = 0; r < 3; ++r) {
            int idx = tops[r];
            int p = L_ / idx;
            p = min(p, L_ / 2);
            p = max(p, 4);
            int n = (L_ - p) / p + 1;
            metaI[r]     = p;
            metaI[3 + r] = n;
            metaI[6 + r] = p * n;
        }
    }
}

// ---------------------------------------------------------------------------
// Patch pipeline for period k, batch chunk [b0, b0+chb):
// resize(p->16) + MLP(16->32->16, exact GELU).
// One 64-lane group = one (b, patch i, 64-feature block).
// flat layout: [chb][FCAP rows j=i*16+t][FN] (f fastest).
// ---------------------------------------------------------------------------
__global__ __launch_bounds__(256)
void patch_mlp_kernel(const float* __restrict__ xs,
                      const float* __restrict__ W1, const float* __restrict__ b1,
                      const float* __restrict__ W2, const float* __restrict__ b2,
                      const int* __restrict__ metaI, float* __restrict__ flat,
                      int k, int b0, int chb)
{
    __shared__ float W1s[512], W2s[512], b1s[32], b2s[16];
    for (int i = threadIdx.x; i < 512; i += 256) { W1s[i] = W1[i]; W2s[i] = W2[i]; }
    if (threadIdx.x < 32) b1s[threadIdx.x] = b1[threadIdx.x];
    if (threadIdx.x < 16) b2s[threadIdx.x] = b2[threadIdx.x];
    __syncthreads();

    const int p = metaI[k], n = metaI[3 + k], tgt = metaI[6 + k];
    const int lane = threadIdx.x & 63;
    const int sub  = threadIdx.x >> 6;
    const float psc = (float)p * 0.0625f;
    const int ITEMS = 8 * NMAX * chb;

    for (int item = (int)blockIdx.x * 4 + sub; item < ITEMS; item += (int)gridDim.x * 4) {
        int bl  = item / (8 * NMAX);
        int rem = item - bl * (8 * NMAX);
        int i   = rem >> 3;
        int fb  = rem & 7;
        if (i >= n) continue;
        int f = fb * 64 + lane;
        const float* xrow = xs + ((size_t)(b0 + bl) * L_ + (size_t)(L_ - tgt) + (size_t)i * p) * FN_ + f;

        float xr[16];
#pragma unroll
        for (int t = 0; t < 16; ++t) {
            float pos = ((float)t + 0.5f) * psc - 0.5f;
            pos = fminf(fmaxf(pos, 0.0f), (float)(p - 1));
            int lo = (int)floorf(pos);
            int hi = min(lo + 1, p - 1);
            float w = pos - (float)lo;
            float vlo = xrow[(size_t)lo * FN_];
            float vhi = xrow[(size_t)hi * FN_];
            xr[t] = vlo * (1.0f - w) + vhi * w;
        }

        float h1[32];
        {
            const float4* B1 = (const float4*)b1s;
#pragma unroll
            for (int u4 = 0; u4 < 8; ++u4) {
                float4 t4 = B1[u4];
                h1[4*u4] = t4.x; h1[4*u4+1] = t4.y; h1[4*u4+2] = t4.z; h1[4*u4+3] = t4.w;
            }
        }
#pragma unroll
        for (int t = 0; t < 16; ++t) {
            float xv = xr[t];
            const float4* Wr = (const float4*)&W1s[t * 32];
#pragma unroll
            for (int u4 = 0; u4 < 8; ++u4) {
                float4 w4 = Wr[u4];
                h1[4*u4]   = fmaf(xv, w4.x, h1[4*u4]);
                h1[4*u4+1] = fmaf(xv, w4.y, h1[4*u4+1]);
                h1[4*u4+2] = fmaf(xv, w4.z, h1[4*u4+2]);
                h1[4*u4+3] = fmaf(xv, w4.w, h1[4*u4+3]);
            }
        }
#pragma unroll
        for (int u = 0; u < 32; ++u) h1[u] = gelu_f(h1[u]);

        float h2[16];
        {
            const float4* B2 = (const float4*)b2s;
#pragma unroll
            for (int v4 = 0; v4 < 4; ++v4) {
                float4 t4 = B2[v4];
                h2[4*v4] = t4.x; h2[4*v4+1] = t4.y; h2[4*v4+2] = t4.z; h2[4*v4+3] = t4.w;
            }
        }
#pragma unroll
        for (int u = 0; u < 32; ++u) {
            float hv = h1[u];
            const float4* Wr = (const float4*)&W2s[u * 16];
#pragma unroll
            for (int v4 = 0; v4 < 4; ++v4) {
                float4 w4 = Wr[v4];
                h2[4*v4]   = fmaf(hv, w4.x, h2[4*v4]);
                h2[4*v4+1] = fmaf(hv, w4.y, h2[4*v4+1]);
                h2[4*v4+2] = fmaf(hv, w4.z, h2[4*v4+2]);
                h2[4*v4+3] = fmaf(hv, w4.w, h2[4*v4+3]);
            }
        }

        size_t obase = ((size_t)bl * FCAP + (size_t)i * 16) * FN_ + f;
#pragma unroll
        for (int t = 0; t < 16; ++t)
            flat[obase + (size_t)t * FN_] = gelu_f(h2[t]);
    }
}

// ---------------------------------------------------------------------------
// Resize flat (n*16 -> 768) and accumulate weighted into fused (d_out, B,L,FN).
// k == 0 initializes (d_out is poisoned before each call).
// ---------------------------------------------------------------------------
__global__ void fuse_acc_kernel(const float* __restrict__ flat,
                                const int* __restrict__ metaI,
                                const float* __restrict__ metaF,
                                float* __restrict__ fused, int k, int b0, int chb)
{
    const int n  = metaI[3 + k];
    const int fl = n * 16;
    const float wk = metaF[k];
    const float sc = (float)fl / 768.0f;
    const int total = chb * L_ * (FN_ / 4);
    for (int idx = blockIdx.x * 256 + threadIdx.x; idx < total; idx += (int)gridDim.x * 256) {
        int f4  = idx & 127;
        int rem = idx >> 7;
        int l   = rem % L_;
        int bl  = rem / L_;
        float pos = ((float)l + 0.5f) * sc - 0.5f;
        pos = fminf(fmaxf(pos, 0.0f), (float)(fl - 1));
        int lo = (int)floorf(pos);
        int hi = min(lo + 1, fl - 1);
        float w = pos - (float)lo;
        const float4 vlo = *(const float4*)&flat[((size_t)bl * FCAP + lo) * FN_ + f4 * 4];
        const float4 vhi = *(const float4*)&flat[((size_t)bl * FCAP + hi) * FN_ + f4 * 4];
        float vx = vlo.x * (1.0f - w) + vhi.x * w;
        float vy = vlo.y * (1.0f - w) + vhi.y * w;
        float vz = vlo.z * (1.0f - w) + vhi.z * w;
        float vw = vlo.w * (1.0f - w) + vhi.w * w;
        size_t o = ((size_t)(b0 + bl) * L_ + l) * FN_ + f4 * 4;
        float4 a;
        if (k == 0) { a.x = 0; a.y = 0; a.z = 0; a.w = 0; }
        else        { a = *(const float4*)&fused[o]; }
        a.x += wk * vx; a.y += wk * vy; a.z += wk * vz; a.w += wk * vw;
        *(float4*)&fused[o] = a;
    }
}

// ---------------------------------------------------------------------------
// Shared fp32 GEMM mainloop: 128x128 tile, K-step 16, 256 threads, 8x8/thread.
// ---------------------------------------------------------------------------
#define TMv ((int)(threadIdx.x & 15))
#define TNv ((int)(threadIdx.x >> 4))

#define GEMM_BODY(APTR, LDA, BPTR, LDB, KDIM)                                          \
    __shared__ float As[16][132];                                                       \
    __shared__ float Bs[16][132];                                                       \
    float acc[8][8];                                                                    \
    _Pragma("unroll") for (int i_ = 0; i_ < 8; ++i_)                                    \
        _Pragma("unroll") for (int j_ = 0; j_ < 8; ++j_) acc[i_][j_] = 0.0f;            \
    const int m0 = blockIdx.y * 128;                                                    \
    const int n0 = blockIdx.x * 128;                                                    \
    for (int k0 = 0; k0 < (KDIM); k0 += 16) {                                           \
        int lm  = (int)(threadIdx.x >> 2);                                              \
        int lk  = (int)(threadIdx.x & 3) * 4;                                           \
        float4 va0 = *(const float4*)&(APTR)[(size_t)(m0 + lm) * (LDA) + (k0 + lk)];    \
        float4 va1 = *(const float4*)&(APTR)[(size_t)(m0 + lm + 64) * (LDA) + (k0 + lk)];\
        int lbk = (int)(threadIdx.x >> 5);                                              \
        int lbn = (int)(threadIdx.x & 31) * 4;                                          \
        float4 vb0 = *(const float4*)&(BPTR)[(size_t)(k0 + lbk) * (LDB) + (n0 + lbn)];  \
        float4 vb1 = *(const float4*)&(BPTR)[(size_t)(k0 + lbk + 8) * (LDB) + (n0 + lbn)];\
        As[lk + 0][lm] = va0.x; As[lk + 1][lm] = va0.y;                                 \
        As[lk + 2][lm] = va0.z; As[lk + 3][lm] = va0.w;                                 \
        As[lk + 0][lm + 64] = va1.x; As[lk + 1][lm + 64] = va1.y;                       \
        As[lk + 2][lm + 64] = va1.z; As[lk + 3][lm + 64] = va1.w;                       \
        *(float4*)&Bs[lbk][lbn]     = vb0;                                              \
        *(float4*)&Bs[lbk + 8][lbn] = vb1;                                              \
        __syncthreads();                                                                \
        _Pragma("unroll") for (int kk = 0; kk < 16; ++kk) {                             \
            float4 a0 = *(const float4*)&As[kk][TMv * 8];                               \
            float4 a1 = *(const float4*)&As[kk][TMv * 8 + 4];                           \
            float4 b0 = *(const float4*)&Bs[kk][TNv * 8];                               \
            float4 b1 = *(const float4*)&Bs[kk][TNv * 8 + 4];                           \
            float am[8] = {a0.x, a0.y, a0.z, a0.w, a1.x, a1.y, a1.z, a1.w};             \
            float bb[8] = {b0.x, b0.y, b0.z, b0.w, b1.x, b1.y, b1.z, b1.w};             \
            _Pragma("unroll") for (int mi = 0; mi < 8; ++mi)                            \
                _Pragma("unroll") for (int ni = 0; ni < 8; ++ni)                        \
                    acc[mi][ni] = fmaf(am[mi], bb[ni], acc[mi][ni]);                    \
        }                                                                               \
        __syncthreads();                                                                \
    }

// proj1: h = gelu(fused_chunk @ Wp1 + bp1)
__global__ __launch_bounds__(256, 2)
void proj1_kernel(const float* __restrict__ A, const float* __restrict__ Bw,
                  const float* __restrict__ bias, float* __restrict__ Hout)
{
    GEMM_BODY(A, FN_, Bw, 2 * FN_, FN_)
    float bv[8];
#pragma unroll
    for (int ni = 0; ni < 8; ++ni) bv[ni] = bias[n0 + TNv * 8 + ni];
#pragma unroll
    for (int mi = 0; mi < 8; ++mi) {
        size_t base = (size_t)(m0 + TMv * 8 + mi) * (size_t)(2 * FN_) + (size_t)(n0 + TNv * 8);
        float4 v0 = {gelu_f(acc[mi][0] + bv[0]), gelu_f(acc[mi][1] + bv[1]),
                     gelu_f(acc[mi][2] + bv[2]), gelu_f(acc[mi][3] + bv[3])};
        float4 v1 = {gelu_f(acc[mi][4] + bv[4]), gelu_f(acc[mi][5] + bv[5]),
                     gelu_f(acc[mi][6] + bv[6]), gelu_f(acc[mi][7] + bv[7])};
        *(float4*)&Hout[base]     = v0;
        *(float4*)&Hout[base + 4] = v1;
    }
}

// proj2 + residual: out[b, nf*L + l] = x[...] + (h @ Wp2)[m, nf] + bp2[nf]
// mbase = global row offset of this chunk.
__global__ __launch_bounds__(256, 2)
void proj2_kernel(const float* __restrict__ A, const float* __restrict__ Bw,
                  const float* __restrict__ bias, const float* __restrict__ xorig,
                  float* __restrict__ outp, int mbase)
{
    GEMM_BODY(A, 2 * FN_, Bw, FN_, 2 * FN_)
    const int m = mbase + m0 + TMv * 8;
    const int b = m / L_;
    const int l = m - b * L_;
#pragma unroll
    for (int ni = 0; ni < 8; ++ni) {
        int nf = n0 + TNv * 8 + ni;
        float bb = bias[nf];
        size_t o = (size_t)b * C_ + (size_t)nf * L_ + l;
        float4 xv0 = *(const float4*)&xorig[o];
        float4 xv1 = *(const float4*)&xorig[o + 4];
        float4 v0 = {xv0.x + acc[0][ni] + bb, xv0.y + acc[1][ni] + bb,
                     xv0.z + acc[2][ni] + bb, xv0.w + acc[3][ni] + bb};
        float4 v1 = {xv1.x + acc[4][ni] + bb, xv1.y + acc[5][ni] + bb,
                     xv1.z + acc[6][ni] + bb, xv1.w + acc[7][ni] + bb};
        *(float4*)&outp[o]     = v0;
        *(float4*)&outp[o + 4] = v1;
    }
}

// Final BN apply in-place on d_out
__global__ void bn2_apply_kernel(float* __restrict__ outp,
                                 const float* __restrict__ scale,
                                 const float* __restrict__ shift)
{
    const int total = B_ * C_ / 4;
    for (int idx = blockIdx.x * 256 + threadIdx.x; idx < total; idx += (int)gridDim.x * 256) {
        int c4 = idx % (C_ / 4);
        float4 v  = ((const float4*)outp)[idx];
        float4 sc = ((const float4*)scale)[c4];
        float4 sh = ((const float4*)shift)[c4];
        v.x = fmaf(v.x, sc.x, sh.x);
        v.y = fmaf(v.y, sc.y, sh.y);
        v.z = fmaf(v.z, sc.z, sh.z);
        v.w = fmaf(v.w, sc.w, sh.w);
        ((float4*)outp)[idx] = v;
    }
}

// ---------------------------------------------------------------------------
// Workspace (floats):
//   scale : 393216        shift : 393216
//   xs    : 25165824      (phase B: aliased by hbuf, 24576 x 1024 = same size)
//   tab2  : 688128        freq : 512   metaI/metaF : 128
//   flat  : CHB * 3072 * 512   (CHB chosen from ws_size; 8 -> 12582912)
// NEED(CHB=8) ~= 157 MB.  fused lives in d_out (B,L,FN); proj2 overwrites
// consumed halves only.
// ---------------------------------------------------------------------------
extern "C" void kernel_launch(void* const* d_in, const int* in_sizes, int n_in,
                              void* d_out, int out_size, void* d_ws, size_t ws_size,
                              hipStream_t stream)
{
    const float* x        = (const float*)d_in[0];
    const float* g_in     = (const float*)d_in[1];
    const float* b_in     = (const float*)d_in[2];
    const float* W1       = (const float*)d_in[3];
    const float* b1       = (const float*)d_in[4];
    const float* W2       = (const float*)d_in[5];
    const float* b2       = (const float*)d_in[6];
    const float* fusion_w = (const float*)d_in[7];
    const float* Wp1      = (const float*)d_in[8];
    const float* bp1      = (const float*)d_in[9];
    const float* Wp2      = (const float*)d_in[10];
    const float* bp2      = (const float*)d_in[11];
    const float* g_out    = (const float*)d_in[12];
    const float* b_out    = (const float*)d_in[13];
    float* out = (float*)d_out;
    float* ws  = (float*)d_ws;

    const size_t o_scale = 0;
    const size_t o_shift = o_scale + C_;
    const size_t o_xs    = o_shift + C_;
    const size_t o_tab   = o_xs + (size_t)B_ * L_ * FN_;
    const size_t o_freq  = o_tab + (size_t)768 * NPAD;
    const size_t o_metaI = o_freq + 512;
    const size_t o_metaF = o_metaI + 64;
    const size_t o_flat  = o_metaF + 64;

    // pick largest batch-chunk that fits
    int CHB = 0;
    {
        const int cands[5] = {16, 8, 4, 2, 1};
        for (int ci = 0; ci < 5; ++ci) {
            size_t need = (o_flat + (size_t)cands[ci] * FCAP * FN_) * sizeof(float);
            if (ws_size >= need) { CHB = cands[ci]; break; }
        }
    }
    if (CHB == 0) return;  // < 113 MB workspace: cannot run

    float* scale = ws + o_scale;
    float* shift = ws + o_shift;
    float* xs    = ws + o_xs;
    float* tab2  = ws + o_tab;
    float* freq  = ws + o_freq;
    int*   metaI = (int*)(ws + o_metaI);
    float* metaF = ws + o_metaF;
    float* flat  = ws + o_flat;
    float* fused = out;            // d_out holds fused until proj2 overwrites
    float* hbuf  = xs;             // phase B: xs is dead, reuse for hidden

    // 1. input BN -> xs
    bn_stats_kernel<<<(C_ / 4 + 255) / 256, 256, 0, stream>>>(x, g_in, b_in, scale, shift);
    bn_apply_xs_kernel<<<dim3(L_ / 32, FN_ / 32, B_), dim3(32, 8), 0, stream>>>(
        x, scale, shift, xs);

    // 2. DFT magnitude spectrum -> periods
    fill_tab2_kernel<<<(768 * NPAD) / 256, 256, 0, stream>>>(tab2, freq);
    dft_gemm_kernel<<<dim3(NPAD / 128, NSIG / 128), 256, 0, stream>>>(xs, tab2, freq);
    topk_kernel<<<1, 64, 0, stream>>>(freq, fusion_w, metaI, metaF);

    // 3. per-period patch pipeline + fusion accumulate (batch-chunked)
    for (int b0 = 0; b0 < B_; b0 += CHB) {
        for (int k = 0; k < 3; ++k) {
            patch_mlp_kernel<<<1024, 256, 0, stream>>>(xs, W1, b1, W2, b2, metaI,
                                                       flat, k, b0, CHB);
            fuse_acc_kernel<<<1024, 256, 0, stream>>>(flat, metaI, metaF,
                                                      fused, k, b0, CHB);
        }
    }

    // 4. channel projection MLP + residual (2 half-batch chunks; each proj2
    //    overwrites only the fused rows its own proj1 already consumed)
    for (int c = 0; c < 2; ++c) {
        const int mrows = B_ * L_ / 2;                 // 24576
        const float* Achunk = fused + (size_t)c * mrows * FN_;
        proj1_kernel<<<dim3(2 * FN_ / 128, mrows / 128), 256, 0, stream>>>(
            Achunk, Wp1, bp1, hbuf);
        proj2_kernel<<<dim3(FN_ / 128, mrows / 128), 256, 0, stream>>>(
            hbuf, Wp2, bp2, x, out, c * mrows);
    }

    // 5. output BN (in-place on d_out)
    bn_stats_kernel<<<(C_ / 4 + 255) / 256, 256, 0, stream>>>(out, g_out, b_out, scale, shift);
    bn2_apply_kernel<<<2048, 256, 0, stream>>>(out, scale, shift);
}